// Round 1
// baseline (659.647 us; speedup 1.0000x reference)
//
#include <hip/hip_runtime.h>
#include <cmath>

#define IN_DIM 128
#define HID 64
#define OUT_DIM 40
#define NREL 8
#define NCOLS 576   // 8*64 (relations) + 64 (root)

// ---------------- pack W blocks + root into one [K x 576] B matrix ----------
__global__ void pack_b1(const float* __restrict__ W, const float* __restrict__ root,
                        float* __restrict__ Bcat) {
  int i = blockIdx.x * blockDim.x + threadIdx.x;
  if (i >= IN_DIM * NCOLS) return;
  int k = i / NCOLS, c = i % NCOLS;
  float v;
  if (c < NREL * HID) {
    int r = c >> 6, o = c & 63;
    v = W[((size_t)r * IN_DIM + k) * HID + o];
  } else {
    v = root[(size_t)k * HID + (c - NREL * HID)];
  }
  Bcat[i] = v;
}

__global__ void pack_b2(const float* __restrict__ W, const float* __restrict__ root,
                        float* __restrict__ Bcat) {
  int i = blockIdx.x * blockDim.x + threadIdx.x;
  if (i >= HID * NCOLS) return;
  int k = i / NCOLS, c = i % NCOLS;
  float v;
  if (c < NREL * HID) {
    int r = c >> 6, o = c & 63;
    v = W[((size_t)r * HID + k) * HID + o];
  } else {
    v = root[(size_t)k * HID + (c - NREL * HID)];
  }
  Bcat[i] = v;
}

// ---------------- degree per (relation, dst) --------------------------------
__global__ void deg_count(const int* __restrict__ dst, const int* __restrict__ et,
                          int* __restrict__ deg, int E, int N) {
  int e = blockIdx.x * blockDim.x + threadIdx.x;
  if (e >= E) return;
  atomicAdd(&deg[(size_t)et[e] * N + dst[e]], 1);
}

__global__ void deg_to_rdeg(int* __restrict__ deg, int n) {
  int i = blockIdx.x * blockDim.x + threadIdx.x;
  if (i >= n) return;
  int d = deg[i];
  float r = 1.0f / (float)(d > 1 ? d : 1);
  ((float*)deg)[i] = r;
}

// ---------------- fp32 tiled GEMM: C[M x 576] = act(A[M x K]) @ B[K x 576] --
// cols 0..511 -> H ; cols 512..575 -> AGG (+bias)
template<int K, bool RELU_A>
__global__ __launch_bounds__(256, 4) void gemm_kernel(
    const float* __restrict__ A,
    const float* __restrict__ B,
    const float* __restrict__ bias,
    float* __restrict__ H,
    float* __restrict__ AGG,
    int M)
{
  constexpr int BK = 64;
  constexpr int ASTR = BK + 4;                 // 68 words: 16B-aligned rows, 2-way banks
  __shared__ float As[64 * ASTR];              // 17408 B
  __shared__ float Bs[BK * 64];                // 16384 B

  int tid = threadIdx.x;
  int row0 = blockIdx.x * 64;
  int cy = blockIdx.y;
  int col0 = cy * 64;

  int tx = tid & 15, ty = tid >> 4;
  int r0 = ty * 4, c0 = tx * 4;
  float acc[4][4] = {};

  for (int k0 = 0; k0 < K; k0 += BK) {
    // stage A tile: 64 rows x BK, coalesced float4 reads
    for (int i = tid; i < 64 * (BK / 4); i += 256) {
      int r  = i / (BK / 4);
      int kq = i % (BK / 4);
      int gr = row0 + r; if (gr >= M) gr = M - 1;
      float4 v = *(const float4*)(A + (size_t)gr * K + k0 + kq * 4);
      if (RELU_A) {
        v.x = fmaxf(v.x, 0.f); v.y = fmaxf(v.y, 0.f);
        v.z = fmaxf(v.z, 0.f); v.w = fmaxf(v.w, 0.f);
      }
      *(float4*)(As + (size_t)r * ASTR + kq * 4) = v;
    }
    // stage B tile: BK x 64
    for (int i = tid; i < BK * 16; i += 256) {
      int k  = i / 16;
      int cq = i % 16;
      float4 v = *(const float4*)(B + (size_t)(k0 + k) * NCOLS + col0 + cq * 4);
      *(float4*)(Bs + k * 64 + cq * 4) = v;
    }
    __syncthreads();

    #pragma unroll 8
    for (int k = 0; k < BK; ++k) {
      float a0 = As[(r0 + 0) * ASTR + k];
      float a1 = As[(r0 + 1) * ASTR + k];
      float a2 = As[(r0 + 2) * ASTR + k];
      float a3 = As[(r0 + 3) * ASTR + k];
      float4 b = *(const float4*)(Bs + k * 64 + c0);
      acc[0][0] += a0 * b.x; acc[0][1] += a0 * b.y; acc[0][2] += a0 * b.z; acc[0][3] += a0 * b.w;
      acc[1][0] += a1 * b.x; acc[1][1] += a1 * b.y; acc[1][2] += a1 * b.z; acc[1][3] += a1 * b.w;
      acc[2][0] += a2 * b.x; acc[2][1] += a2 * b.y; acc[2][2] += a2 * b.z; acc[2][3] += a2 * b.w;
      acc[3][0] += a3 * b.x; acc[3][1] += a3 * b.y; acc[3][2] += a3 * b.z; acc[3][3] += a3 * b.w;
    }
    __syncthreads();
  }

  #pragma unroll
  for (int ii = 0; ii < 4; ++ii) {
    int gr = row0 + r0 + ii;
    if (gr >= M) continue;
    float4 v = make_float4(acc[ii][0], acc[ii][1], acc[ii][2], acc[ii][3]);
    if (cy < 8) {
      *(float4*)(H + (size_t)gr * (NREL * HID) + col0 + c0) = v;
    } else {
      float4 bb = *(const float4*)(bias + c0);
      v.x += bb.x; v.y += bb.y; v.z += bb.z; v.w += bb.w;
      *(float4*)(AGG + (size_t)gr * HID + c0) = v;
    }
  }
}

// ---------------- per-edge scatter: AGG[dst] += H[src][type*64+lane]/deg ----
__global__ __launch_bounds__(256) void edge_agg(
    const float* __restrict__ H, const float* __restrict__ rdeg,
    const int* __restrict__ src, const int* __restrict__ dst,
    const int* __restrict__ et,
    float* __restrict__ AGG, int E, int N)
{
  int e = blockIdx.x * 4 + (threadIdx.x >> 6);
  if (e >= E) return;
  int lane = threadIdx.x & 63;
  int s = src[e], d = dst[e], t = et[e];
  float w = rdeg[(size_t)t * N + d];
  float v = H[(size_t)s * (NREL * HID) + t * HID + lane] * w;
  atomicAdd(AGG + (size_t)d * HID + lane, v);
}

// ---------------- final: relu -> @Wl+bl -> log_softmax ----------------------
__global__ __launch_bounds__(256) void final_k(
    const float* __restrict__ AGG, const float* __restrict__ Wl,
    const float* __restrict__ bl, float* __restrict__ out, int N)
{
  __shared__ float sW[HID * OUT_DIM];
  __shared__ float sb[OUT_DIM];
  int tid = threadIdx.x;
  for (int i = tid; i < HID * OUT_DIM; i += 256) sW[i] = Wl[i];
  if (tid < OUT_DIM) sb[tid] = bl[tid];
  __syncthreads();

  int n = blockIdx.x * 256 + tid;
  if (n >= N) return;

  float acc[OUT_DIM];
  #pragma unroll
  for (int j = 0; j < OUT_DIM; ++j) acc[j] = sb[j];

  const float* row = AGG + (size_t)n * HID;
  for (int k = 0; k < HID; ++k) {
    float a = fmaxf(row[k], 0.f);
    #pragma unroll
    for (int j = 0; j < OUT_DIM; ++j) acc[j] += a * sW[k * OUT_DIM + j];
  }

  float m = acc[0];
  #pragma unroll
  for (int j = 1; j < OUT_DIM; ++j) m = fmaxf(m, acc[j]);
  float s = 0.f;
  #pragma unroll
  for (int j = 0; j < OUT_DIM; ++j) s += expf(acc[j] - m);
  float lse = m + logf(s);
  float* o = out + (size_t)n * OUT_DIM;
  #pragma unroll
  for (int j = 0; j < OUT_DIM; ++j) o[j] = acc[j] - lse;
}

// ---------------- launch ----------------------------------------------------
extern "C" void kernel_launch(void* const* d_in, const int* in_sizes, int n_in,
                              void* d_out, int out_size, void* d_ws, size_t ws_size,
                              hipStream_t stream) {
  const float* x     = (const float*)d_in[0];
  const int*   eidx  = (const int*)d_in[1];
  const int*   etype = (const int*)d_in[2];
  const float* W1    = (const float*)d_in[3];
  const float* root1 = (const float*)d_in[4];
  const float* b1    = (const float*)d_in[5];
  const float* W2    = (const float*)d_in[6];
  const float* root2 = (const float*)d_in[7];
  const float* b2    = (const float*)d_in[8];
  const float* Wl    = (const float*)d_in[9];
  const float* bl    = (const float*)d_in[10];

  int N = in_sizes[0] / IN_DIM;   // 50000
  int E = in_sizes[2];            // 800000
  const int* srcp = eidx;
  const int* dstp = eidx + E;

  char* ws = (char*)d_ws;
  size_t off = 0;
  auto alloc = [&](size_t bytes) -> char* {
    char* p = ws + off;
    off += (bytes + 255) & ~(size_t)255;
    return p;
  };
  float* Bcat1 = (float*)alloc((size_t)IN_DIM * NCOLS * 4);
  float* Bcat2 = (float*)alloc((size_t)HID * NCOLS * 4);
  int*   deg   = (int*)alloc((size_t)NREL * N * 4);
  float* H     = (float*)alloc((size_t)N * NREL * HID * 4);   // 102.4 MB
  float* AGG1  = (float*)alloc((size_t)N * HID * 4);
  float* AGG2  = (float*)alloc((size_t)N * HID * 4);

  hipMemsetAsync(deg, 0, (size_t)NREL * N * 4, stream);
  pack_b1<<<(IN_DIM * NCOLS + 255) / 256, 256, 0, stream>>>(W1, root1, Bcat1);
  pack_b2<<<(HID * NCOLS + 255) / 256, 256, 0, stream>>>(W2, root2, Bcat2);
  deg_count<<<(E + 255) / 256, 256, 0, stream>>>(dstp, etype, deg, E, N);
  deg_to_rdeg<<<(NREL * N + 255) / 256, 256, 0, stream>>>(deg, NREL * N);

  dim3 gg((N + 63) / 64, 9);
  gemm_kernel<IN_DIM, false><<<gg, 256, 0, stream>>>(x, Bcat1, b1, H, AGG1, N);
  edge_agg<<<(E + 3) / 4, 256, 0, stream>>>(H, (const float*)deg, srcp, dstp, etype, AGG1, E, N);
  gemm_kernel<HID, true><<<gg, 256, 0, stream>>>(AGG1, Bcat2, b2, H, AGG2, N);
  edge_agg<<<(E + 3) / 4, 256, 0, stream>>>(H, (const float*)deg, srcp, dstp, etype, AGG2, E, N);
  final_k<<<(N + 255) / 256, 256, 0, stream>>>(AGG2, Wl, bl, (float*)d_out, N);
}

// Round 2
// 574.733 us; speedup vs baseline: 1.1477x; 1.1477x over previous
//
#include <hip/hip_runtime.h>
#include <cmath>

#define IN_DIM 128
#define HID 64
#define OUT_DIM 40
#define NREL 8
#define NCOLS 576   // 8*64 (relations) + 64 (root)

// ---------------- pack W blocks + root into one [K x 576] B matrix ----------
__global__ void pack_b1(const float* __restrict__ W, const float* __restrict__ root,
                        float* __restrict__ Bcat) {
  int i = blockIdx.x * blockDim.x + threadIdx.x;
  if (i >= IN_DIM * NCOLS) return;
  int k = i / NCOLS, c = i % NCOLS;
  float v;
  if (c < NREL * HID) {
    int r = c >> 6, o = c & 63;
    v = W[((size_t)r * IN_DIM + k) * HID + o];
  } else {
    v = root[(size_t)k * HID + (c - NREL * HID)];
  }
  Bcat[i] = v;
}

__global__ void pack_b2(const float* __restrict__ W, const float* __restrict__ root,
                        float* __restrict__ Bcat) {
  int i = blockIdx.x * blockDim.x + threadIdx.x;
  if (i >= HID * NCOLS) return;
  int k = i / NCOLS, c = i % NCOLS;
  float v;
  if (c < NREL * HID) {
    int r = c >> 6, o = c & 63;
    v = W[((size_t)r * HID + k) * HID + o];
  } else {
    v = root[(size_t)k * HID + (c - NREL * HID)];
  }
  Bcat[i] = v;
}

// ---------------- degree per (relation, dst) + total in-degree --------------
__global__ void deg_count(const int* __restrict__ dst, const int* __restrict__ et,
                          int* __restrict__ deg, int* __restrict__ cnt, int E, int N) {
  int e = blockIdx.x * blockDim.x + threadIdx.x;
  if (e >= E) return;
  int d = dst[e];
  atomicAdd(&deg[(size_t)et[e] * N + d], 1);
  atomicAdd(&cnt[d], 1);
}

__global__ void deg_to_rdeg(int* __restrict__ deg, int n) {
  int i = blockIdx.x * blockDim.x + threadIdx.x;
  if (i >= n) return;
  int d = deg[i];
  float r = 1.0f / (float)(d > 1 ? d : 1);
  ((float*)deg)[i] = r;
}

// ---------------- exclusive scan over cnt[N] -> offs[N+1], cursor[N] --------
#define SCAN_B 512

__global__ void scan1(const int* __restrict__ cnt, int* __restrict__ bsum, int N) {
  __shared__ int sh[SCAN_B];
  int i = blockIdx.x * SCAN_B + threadIdx.x;
  sh[threadIdx.x] = (i < N) ? cnt[i] : 0;
  __syncthreads();
  for (int s = SCAN_B / 2; s > 0; s >>= 1) {
    if (threadIdx.x < s) sh[threadIdx.x] += sh[threadIdx.x + s];
    __syncthreads();
  }
  if (threadIdx.x == 0) bsum[blockIdx.x] = sh[0];
}

// single block, exclusive-scans nb (<=128) block sums in place
__global__ void scan2(int* __restrict__ bsum, int nb) {
  __shared__ int sh[128];
  int t = threadIdx.x;
  sh[t] = (t < nb) ? bsum[t] : 0;
  __syncthreads();
  for (int off = 1; off < 128; off <<= 1) {
    int x = sh[t];
    if (t >= off) x += sh[t - off];
    __syncthreads();
    sh[t] = x;
    __syncthreads();
  }
  if (t < nb) bsum[t] = (t == 0) ? 0 : sh[t - 1];
}

__global__ void scan3(const int* __restrict__ cnt, const int* __restrict__ bsum,
                      int* __restrict__ offs, int* __restrict__ cursor, int N, int E) {
  __shared__ int sh[SCAN_B];
  int i = blockIdx.x * SCAN_B + threadIdx.x;
  int v = (i < N) ? cnt[i] : 0;
  sh[threadIdx.x] = v;
  __syncthreads();
  for (int off = 1; off < SCAN_B; off <<= 1) {
    int x = sh[threadIdx.x];
    if (threadIdx.x >= off) x += sh[threadIdx.x - off];
    __syncthreads();
    sh[threadIdx.x] = x;
    __syncthreads();
  }
  int excl = (threadIdx.x == 0) ? 0 : sh[threadIdx.x - 1];
  int base = bsum[blockIdx.x];
  if (i < N) { offs[i] = base + excl; cursor[i] = base + excl; }
  if (i == 0) offs[N] = E;
}

// ---------------- scatter edges into CSR-by-dst -----------------------------
__global__ void scatter_edges(const int* __restrict__ src, const int* __restrict__ dst,
                              const int* __restrict__ et, int* __restrict__ cursor,
                              int* __restrict__ eval, int E) {
  int e = blockIdx.x * blockDim.x + threadIdx.x;
  if (e >= E) return;
  int d = dst[e];
  int pos = atomicAdd(&cursor[d], 1);
  eval[pos] = (src[e] << 3) | et[e];
}

// ---------------- fp32 tiled GEMM: C[M x 576] = act(A[M x K]) @ B[K x 576] --
// cols 0..511 -> H ; cols 512..575 -> AGG (+bias)
template<int K, bool RELU_A>
__global__ __launch_bounds__(256, 4) void gemm_kernel(
    const float* __restrict__ A,
    const float* __restrict__ B,
    const float* __restrict__ bias,
    float* __restrict__ H,
    float* __restrict__ AGG,
    int M)
{
  constexpr int BK = 64;
  constexpr int ASTR = BK + 4;
  __shared__ float As[64 * ASTR];
  __shared__ float Bs[BK * 64];

  int tid = threadIdx.x;
  int row0 = blockIdx.x * 64;
  int cy = blockIdx.y;
  int col0 = cy * 64;

  int tx = tid & 15, ty = tid >> 4;
  int r0 = ty * 4, c0 = tx * 4;
  float acc[4][4] = {};

  for (int k0 = 0; k0 < K; k0 += BK) {
    for (int i = tid; i < 64 * (BK / 4); i += 256) {
      int r  = i / (BK / 4);
      int kq = i % (BK / 4);
      int gr = row0 + r; if (gr >= M) gr = M - 1;
      float4 v = *(const float4*)(A + (size_t)gr * K + k0 + kq * 4);
      if (RELU_A) {
        v.x = fmaxf(v.x, 0.f); v.y = fmaxf(v.y, 0.f);
        v.z = fmaxf(v.z, 0.f); v.w = fmaxf(v.w, 0.f);
      }
      *(float4*)(As + (size_t)r * ASTR + kq * 4) = v;
    }
    for (int i = tid; i < BK * 16; i += 256) {
      int k  = i / 16;
      int cq = i % 16;
      float4 v = *(const float4*)(B + (size_t)(k0 + k) * NCOLS + col0 + cq * 4);
      *(float4*)(Bs + k * 64 + cq * 4) = v;
    }
    __syncthreads();

    #pragma unroll 8
    for (int k = 0; k < BK; ++k) {
      float a0 = As[(r0 + 0) * ASTR + k];
      float a1 = As[(r0 + 1) * ASTR + k];
      float a2 = As[(r0 + 2) * ASTR + k];
      float a3 = As[(r0 + 3) * ASTR + k];
      float4 b = *(const float4*)(Bs + k * 64 + c0);
      acc[0][0] += a0 * b.x; acc[0][1] += a0 * b.y; acc[0][2] += a0 * b.z; acc[0][3] += a0 * b.w;
      acc[1][0] += a1 * b.x; acc[1][1] += a1 * b.y; acc[1][2] += a1 * b.z; acc[1][3] += a1 * b.w;
      acc[2][0] += a2 * b.x; acc[2][1] += a2 * b.y; acc[2][2] += a2 * b.z; acc[2][3] += a2 * b.w;
      acc[3][0] += a3 * b.x; acc[3][1] += a3 * b.y; acc[3][2] += a3 * b.z; acc[3][3] += a3 * b.w;
    }
    __syncthreads();
  }

  #pragma unroll
  for (int ii = 0; ii < 4; ++ii) {
    int gr = row0 + r0 + ii;
    if (gr >= M) continue;
    float4 v = make_float4(acc[ii][0], acc[ii][1], acc[ii][2], acc[ii][3]);
    if (cy < 8) {
      *(float4*)(H + (size_t)gr * (NREL * HID) + col0 + c0) = v;
    } else {
      float4 bb = *(const float4*)(bias + c0);
      v.x += bb.x; v.y += bb.y; v.z += bb.z; v.w += bb.w;
      *(float4*)(AGG + (size_t)gr * HID + c0) = v;
    }
  }
}

// ---------------- CSR aggregation: one wave per dst node, no atomics --------
__global__ __launch_bounds__(256) void csr_agg(
    const float* __restrict__ H, const float* __restrict__ rdeg,
    const int* __restrict__ offs, const int* __restrict__ eval,
    float* __restrict__ AGG, int N)
{
  int d = blockIdx.x * 4 + (threadIdx.x >> 6);
  if (d >= N) return;
  int lane = threadIdx.x & 63;
  int beg = offs[d], end = offs[d + 1];
  float acc = AGG[(size_t)d * HID + lane];   // root + bias part from GEMM
  for (int p = beg; p < end; ++p) {
    int v = eval[p];
    int s = v >> 3, t = v & 7;
    float w = rdeg[(size_t)t * N + d];
    acc += H[(size_t)s * (NREL * HID) + t * HID + lane] * w;
  }
  AGG[(size_t)d * HID + lane] = acc;
}

// ---------------- final: relu -> @Wl+bl -> log_softmax ----------------------
__global__ __launch_bounds__(256) void final_k(
    const float* __restrict__ AGG, const float* __restrict__ Wl,
    const float* __restrict__ bl, float* __restrict__ out, int N)
{
  __shared__ float sW[HID * OUT_DIM];
  __shared__ float sb[OUT_DIM];
  int tid = threadIdx.x;
  for (int i = tid; i < HID * OUT_DIM; i += 256) sW[i] = Wl[i];
  if (tid < OUT_DIM) sb[tid] = bl[tid];
  __syncthreads();

  int n = blockIdx.x * 256 + tid;
  if (n >= N) return;

  float acc[OUT_DIM];
  #pragma unroll
  for (int j = 0; j < OUT_DIM; ++j) acc[j] = sb[j];

  const float* row = AGG + (size_t)n * HID;
  for (int k = 0; k < HID; ++k) {
    float a = fmaxf(row[k], 0.f);
    #pragma unroll
    for (int j = 0; j < OUT_DIM; ++j) acc[j] += a * sW[k * OUT_DIM + j];
  }

  float m = acc[0];
  #pragma unroll
  for (int j = 1; j < OUT_DIM; ++j) m = fmaxf(m, acc[j]);
  float s = 0.f;
  #pragma unroll
  for (int j = 0; j < OUT_DIM; ++j) s += expf(acc[j] - m);
  float lse = m + logf(s);
  float* o = out + (size_t)n * OUT_DIM;
  #pragma unroll
  for (int j = 0; j < OUT_DIM; ++j) o[j] = acc[j] - lse;
}

// ---------------- launch ----------------------------------------------------
extern "C" void kernel_launch(void* const* d_in, const int* in_sizes, int n_in,
                              void* d_out, int out_size, void* d_ws, size_t ws_size,
                              hipStream_t stream) {
  const float* x     = (const float*)d_in[0];
  const int*   eidx  = (const int*)d_in[1];
  const int*   etype = (const int*)d_in[2];
  const float* W1    = (const float*)d_in[3];
  const float* root1 = (const float*)d_in[4];
  const float* b1    = (const float*)d_in[5];
  const float* W2    = (const float*)d_in[6];
  const float* root2 = (const float*)d_in[7];
  const float* b2    = (const float*)d_in[8];
  const float* Wl    = (const float*)d_in[9];
  const float* bl    = (const float*)d_in[10];

  int N = in_sizes[0] / IN_DIM;   // 50000
  int E = in_sizes[2];            // 800000
  const int* srcp = eidx;
  const int* dstp = eidx + E;

  char* ws = (char*)d_ws;
  size_t off = 0;
  auto alloc = [&](size_t bytes) -> char* {
    char* p = ws + off;
    off += (bytes + 255) & ~(size_t)255;
    return p;
  };
  float* Bcat1 = (float*)alloc((size_t)IN_DIM * NCOLS * 4);
  float* Bcat2 = (float*)alloc((size_t)HID * NCOLS * 4);
  int*   deg   = (int*)alloc((size_t)NREL * N * 4);
  int*   cnt   = (int*)alloc((size_t)N * 4);
  int*   offs  = (int*)alloc((size_t)(N + 1) * 4);
  int*   cursor= (int*)alloc((size_t)N * 4);
  int*   bsum  = (int*)alloc(128 * 4);
  int*   eval  = (int*)alloc((size_t)E * 4);
  float* H     = (float*)alloc((size_t)N * NREL * HID * 4);   // 102.4 MB
  float* AGG1  = (float*)alloc((size_t)N * HID * 4);
  float* AGG2  = (float*)alloc((size_t)N * HID * 4);

  int nb = (N + SCAN_B - 1) / SCAN_B;   // 98 blocks

  hipMemsetAsync(deg, 0, (size_t)NREL * N * 4, stream);
  hipMemsetAsync(cnt, 0, (size_t)N * 4, stream);
  pack_b1<<<(IN_DIM * NCOLS + 255) / 256, 256, 0, stream>>>(W1, root1, Bcat1);
  pack_b2<<<(HID * NCOLS + 255) / 256, 256, 0, stream>>>(W2, root2, Bcat2);
  deg_count<<<(E + 255) / 256, 256, 0, stream>>>(dstp, etype, deg, cnt, E, N);
  deg_to_rdeg<<<(NREL * N + 255) / 256, 256, 0, stream>>>(deg, NREL * N);

  scan1<<<nb, SCAN_B, 0, stream>>>(cnt, bsum, N);
  scan2<<<1, 128, 0, stream>>>(bsum, nb);
  scan3<<<nb, SCAN_B, 0, stream>>>(cnt, bsum, offs, cursor, N, E);
  scatter_edges<<<(E + 255) / 256, 256, 0, stream>>>(srcp, dstp, etype, cursor, eval, E);

  dim3 gg((N + 63) / 64, 9);
  gemm_kernel<IN_DIM, false><<<gg, 256, 0, stream>>>(x, Bcat1, b1, H, AGG1, N);
  csr_agg<<<(N + 3) / 4, 256, 0, stream>>>(H, (const float*)deg, offs, eval, AGG1, N);
  gemm_kernel<HID, true><<<gg, 256, 0, stream>>>(AGG1, Bcat2, b2, H, AGG2, N);
  csr_agg<<<(N + 3) / 4, 256, 0, stream>>>(H, (const float*)deg, offs, eval, AGG2, N);
  final_k<<<(N + 255) / 256, 256, 0, stream>>>(AGG2, Wl, bl, (float*)d_out, N);
}

// Round 3
// 407.400 us; speedup vs baseline: 1.6192x; 1.4107x over previous
//
#include <hip/hip_runtime.h>
#include <hip/hip_bf16.h>
#include <cmath>

#define IN_DIM 128
#define HID 64
#define OUT_DIM 40
#define NREL 8
#define NCOLS 576   // 8*64 (relations) + 64 (root)

typedef __attribute__((ext_vector_type(8))) short short8;
typedef __attribute__((ext_vector_type(4))) short short4v;
typedef __attribute__((ext_vector_type(4))) float floatx4;

static __device__ __forceinline__ short f2bf(float f) {
  __hip_bfloat16 h = __float2bfloat16(f);
  return __builtin_bit_cast(short, h);
}
static __device__ __forceinline__ float bf2f(short s) {
  __hip_bfloat16 h = __builtin_bit_cast(__hip_bfloat16, s);
  return __bfloat162float(h);
}

// ---- pack W[R][K][64] + root[K][64] into Bt[576][K] bf16 (K-major) ---------
__global__ void pack_bt(const float* __restrict__ W, const float* __restrict__ root,
                        short* __restrict__ Bt, int K) {
  int i = blockIdx.x * blockDim.x + threadIdx.x;
  if (i >= NCOLS * K) return;
  int c = i / K, k = i % K;
  float v;
  if (c < NREL * HID) {
    v = W[((size_t)(c >> 6) * K + k) * HID + (c & 63)];
  } else {
    v = root[(size_t)k * HID + (c - NREL * HID)];
  }
  Bt[i] = f2bf(v);
}

// ---- degree per (relation, dst) --------------------------------------------
__global__ void deg_count(const int* __restrict__ dst, const int* __restrict__ et,
                          int* __restrict__ deg, int E, int N) {
  int e = blockIdx.x * blockDim.x + threadIdx.x;
  if (e >= E) return;
  atomicAdd(&deg[(size_t)et[e] * N + dst[e]], 1);
}

__global__ void cnt_from_deg(const int* __restrict__ deg, int* __restrict__ cnt, int N) {
  int d = blockIdx.x * blockDim.x + threadIdx.x;
  if (d >= N) return;
  int s = 0;
  #pragma unroll
  for (int r = 0; r < NREL; ++r) s += deg[(size_t)r * N + d];
  cnt[d] = s;
}

__global__ void deg_to_rdeg(const int* __restrict__ deg, float* __restrict__ rdeg, int n) {
  int i = blockIdx.x * blockDim.x + threadIdx.x;
  if (i >= n) return;
  int d = deg[i];
  rdeg[i] = 1.0f / (float)(d > 1 ? d : 1);
}

// ---- exclusive scan over cnt[N] -> offs[N+1], cursor[N] --------------------
#define SCAN_B 512

__global__ void scan1(const int* __restrict__ cnt, int* __restrict__ bsum, int N) {
  __shared__ int sh[SCAN_B];
  int i = blockIdx.x * SCAN_B + threadIdx.x;
  sh[threadIdx.x] = (i < N) ? cnt[i] : 0;
  __syncthreads();
  for (int s = SCAN_B / 2; s > 0; s >>= 1) {
    if (threadIdx.x < s) sh[threadIdx.x] += sh[threadIdx.x + s];
    __syncthreads();
  }
  if (threadIdx.x == 0) bsum[blockIdx.x] = sh[0];
}

__global__ void scan2(int* __restrict__ bsum, int nb) {
  __shared__ int sh[128];
  int t = threadIdx.x;
  sh[t] = (t < nb) ? bsum[t] : 0;
  __syncthreads();
  for (int off = 1; off < 128; off <<= 1) {
    int x = sh[t];
    if (t >= off) x += sh[t - off];
    __syncthreads();
    sh[t] = x;
    __syncthreads();
  }
  if (t < nb) bsum[t] = (t == 0) ? 0 : sh[t - 1];
}

__global__ void scan3(const int* __restrict__ cnt, const int* __restrict__ bsum,
                      int* __restrict__ offs, int* __restrict__ cursor, int N, int E) {
  __shared__ int sh[SCAN_B];
  int i = blockIdx.x * SCAN_B + threadIdx.x;
  int v = (i < N) ? cnt[i] : 0;
  sh[threadIdx.x] = v;
  __syncthreads();
  for (int off = 1; off < SCAN_B; off <<= 1) {
    int x = sh[threadIdx.x];
    if (threadIdx.x >= off) x += sh[threadIdx.x - off];
    __syncthreads();
    sh[threadIdx.x] = x;
    __syncthreads();
  }
  int excl = (threadIdx.x == 0) ? 0 : sh[threadIdx.x - 1];
  int base = bsum[blockIdx.x];
  if (i < N) { offs[i] = base + excl; cursor[i] = base + excl; }
  if (i == 0) offs[N] = E;
}

// ---- scatter edges into CSR-by-dst with precomputed weight -----------------
__global__ void scatter_edges(const int* __restrict__ src, const int* __restrict__ dst,
                              const int* __restrict__ et, const float* __restrict__ rdeg,
                              int* __restrict__ cursor, int2* __restrict__ ev,
                              int E, int N) {
  int e = blockIdx.x * blockDim.x + threadIdx.x;
  if (e >= E) return;
  int d = dst[e], t = et[e];
  int pos = atomicAdd(&cursor[d], 1);
  int2 v;
  v.x = (src[e] << 3) | t;
  v.y = __float_as_int(rdeg[(size_t)t * N + d]);
  ev[pos] = v;
}

// ---- MFMA bf16 GEMM: C[M x 576] = act(A[M x K]) @ Bt^T ---------------------
// Block: 64 rows x 576 cols (9 col-tiles looped). A staged ONCE in LDS.
// cols 0..511 -> H (bf16); cols 512..575 -> AGG (fp32, +bias)
template<int K, bool RELU_A>
__global__ __launch_bounds__(256, 4) void gemm_mfma(
    const float* __restrict__ A,     // [M][K] fp32
    const short* __restrict__ Bt,    // [576][K] bf16, K-major
    const float* __restrict__ bias,  // [64]
    short* __restrict__ H,           // [M][512] bf16
    float* __restrict__ AGG,         // [M][64] fp32
    int M)
{
  constexpr int AST = K + 8;                  // +16B pad: banks 2-way max
  __shared__ short As[64 * AST];
  __shared__ short Bs[64 * AST];

  int tid = threadIdx.x;
  int row0 = blockIdx.x * 64;
  int wv = tid >> 6, lane = tid & 63;
  int lm = lane & 15, quad = lane >> 4;

  // stage A tile [64 x K] as bf16, K-major, coalesced float4 reads
  constexpr int CH = K / 4;
  for (int i = tid; i < 64 * CH; i += 256) {
    int r = i / CH, kq = i % CH;
    int gr = row0 + r; if (gr >= M) gr = M - 1;
    float4 v = *(const float4*)(A + (size_t)gr * K + kq * 4);
    if (RELU_A) {
      v.x = fmaxf(v.x, 0.f); v.y = fmaxf(v.y, 0.f);
      v.z = fmaxf(v.z, 0.f); v.w = fmaxf(v.w, 0.f);
    }
    short4v s;
    s.x = f2bf(v.x); s.y = f2bf(v.y); s.z = f2bf(v.z); s.w = f2bf(v.w);
    *(short4v*)(As + r * AST + kq * 4) = s;
  }

  const short* ap = As + (16 * wv + lm) * AST + quad * 8;

  for (int cy = 0; cy < 9; ++cy) {
    // stage B tile: rows cy*64 .. +63 of Bt, K-major, coalesced 16B reads
    constexpr int CB = K / 8;
    for (int i = tid; i < 64 * CB; i += 256) {
      int n = i / CB, ko = i % CB;
      short8 v = *(const short8*)(Bt + (size_t)(cy * 64 + n) * K + ko * 8);
      *(short8*)(Bs + n * AST + ko * 8) = v;
    }
    __syncthreads();

    floatx4 acc[4] = {{0,0,0,0},{0,0,0,0},{0,0,0,0},{0,0,0,0}};
    #pragma unroll
    for (int ks = 0; ks < K / 32; ++ks) {
      short8 a = *(const short8*)(ap + ks * 32);
      #pragma unroll
      for (int nb = 0; nb < 4; ++nb) {
        short8 b = *(const short8*)(Bs + (nb * 16 + lm) * AST + ks * 32 + quad * 8);
        acc[nb] = __builtin_amdgcn_mfma_f32_16x16x32_bf16(a, b, acc[nb], 0, 0, 0);
      }
    }
    __syncthreads();   // all waves done reading Bs before next staging

    // epilogue: C/D layout col=lane&15, row=quad*4+reg  [m89-verified]
    int mbase = row0 + 16 * wv + quad * 4;
    if (cy < 8) {
      #pragma unroll
      for (int nb = 0; nb < 4; ++nb) {
        int col = cy * 64 + nb * 16 + lm;
        #pragma unroll
        for (int r = 0; r < 4; ++r) {
          int mg = mbase + r;
          if (mg < M) H[(size_t)mg * (NREL * HID) + col] = f2bf(acc[nb][r]);
        }
      }
    } else {
      #pragma unroll
      for (int nb = 0; nb < 4; ++nb) {
        int col = nb * 16 + lm;
        float bv = bias[col];
        #pragma unroll
        for (int r = 0; r < 4; ++r) {
          int mg = mbase + r;
          if (mg < M) AGG[(size_t)mg * HID + col] = acc[nb][r] + bv;
        }
      }
    }
  }
}

// ---- CSR aggregation: one wave per dst node, bf16 gathers, no atomics ------
__global__ __launch_bounds__(256) void csr_agg(
    const short* __restrict__ H, const int* __restrict__ offs,
    const int2* __restrict__ ev, float* __restrict__ AGG, int N)
{
  int d = blockIdx.x * 4 + (threadIdx.x >> 6);
  if (d >= N) return;
  int lane = threadIdx.x & 63;
  int beg = offs[d], end = offs[d + 1];
  float acc = AGG[(size_t)d * HID + lane];   // root + bias part from GEMM
  for (int p = beg; p < end; ++p) {
    int2 e = ev[p];
    int s = e.x >> 3, t = e.x & 7;
    float w = __int_as_float(e.y);
    acc += bf2f(H[(size_t)s * (NREL * HID) + t * HID + lane]) * w;
  }
  AGG[(size_t)d * HID + lane] = acc;
}

// ---- final: relu -> @Wl+bl -> log_softmax ----------------------------------
__global__ __launch_bounds__(256) void final_k(
    const float* __restrict__ AGG, const float* __restrict__ Wl,
    const float* __restrict__ bl, float* __restrict__ out, int N)
{
  __shared__ float sW[HID * OUT_DIM];
  __shared__ float sb[OUT_DIM];
  int tid = threadIdx.x;
  for (int i = tid; i < HID * OUT_DIM; i += 256) sW[i] = Wl[i];
  if (tid < OUT_DIM) sb[tid] = bl[tid];
  __syncthreads();

  int n = blockIdx.x * 256 + tid;
  if (n >= N) return;

  float acc[OUT_DIM];
  #pragma unroll
  for (int j = 0; j < OUT_DIM; ++j) acc[j] = sb[j];

  const float* row = AGG + (size_t)n * HID;
  for (int k = 0; k < HID; ++k) {
    float a = fmaxf(row[k], 0.f);
    #pragma unroll
    for (int j = 0; j < OUT_DIM; ++j) acc[j] += a * sW[k * OUT_DIM + j];
  }

  float m = acc[0];
  #pragma unroll
  for (int j = 1; j < OUT_DIM; ++j) m = fmaxf(m, acc[j]);
  float s = 0.f;
  #pragma unroll
  for (int j = 0; j < OUT_DIM; ++j) s += expf(acc[j] - m);
  float lse = m + logf(s);
  float* o = out + (size_t)n * OUT_DIM;
  #pragma unroll
  for (int j = 0; j < OUT_DIM; ++j) o[j] = acc[j] - lse;
}

// ---- launch ----------------------------------------------------------------
extern "C" void kernel_launch(void* const* d_in, const int* in_sizes, int n_in,
                              void* d_out, int out_size, void* d_ws, size_t ws_size,
                              hipStream_t stream) {
  const float* x     = (const float*)d_in[0];
  const int*   eidx  = (const int*)d_in[1];
  const int*   etype = (const int*)d_in[2];
  const float* W1    = (const float*)d_in[3];
  const float* root1 = (const float*)d_in[4];
  const float* b1    = (const float*)d_in[5];
  const float* W2    = (const float*)d_in[6];
  const float* root2 = (const float*)d_in[7];
  const float* b2    = (const float*)d_in[8];
  const float* Wl    = (const float*)d_in[9];
  const float* bl    = (const float*)d_in[10];

  int N = in_sizes[0] / IN_DIM;   // 50000
  int E = in_sizes[2];            // 800000
  const int* srcp = eidx;
  const int* dstp = eidx + E;

  char* ws = (char*)d_ws;
  size_t off = 0;
  auto alloc = [&](size_t bytes) -> char* {
    char* p = ws + off;
    off += (bytes + 255) & ~(size_t)255;
    return p;
  };
  short* Bt1   = (short*)alloc((size_t)NCOLS * IN_DIM * 2);
  short* Bt2   = (short*)alloc((size_t)NCOLS * HID * 2);
  int*   deg   = (int*)alloc((size_t)NREL * N * 4);
  float* rdeg  = (float*)alloc((size_t)NREL * N * 4);
  int*   cnt   = (int*)alloc((size_t)N * 4);
  int*   offs  = (int*)alloc((size_t)(N + 1) * 4);
  int*   cursor= (int*)alloc((size_t)N * 4);
  int*   bsum  = (int*)alloc(128 * 4);
  int2*  ev    = (int2*)alloc((size_t)E * 8);
  short* H     = (short*)alloc((size_t)N * NREL * HID * 2);  // 51.2 MB bf16
  float* AGG1  = (float*)alloc((size_t)N * HID * 4);
  float* AGG2  = (float*)alloc((size_t)N * HID * 4);

  int nb = (N + SCAN_B - 1) / SCAN_B;   // 98 blocks

  hipMemsetAsync(deg, 0, (size_t)NREL * N * 4, stream);
  pack_bt<<<(NCOLS * IN_DIM + 255) / 256, 256, 0, stream>>>(W1, root1, Bt1, IN_DIM);
  pack_bt<<<(NCOLS * HID + 255) / 256, 256, 0, stream>>>(W2, root2, Bt2, HID);
  deg_count<<<(E + 255) / 256, 256, 0, stream>>>(dstp, etype, deg, E, N);
  cnt_from_deg<<<(N + 255) / 256, 256, 0, stream>>>(deg, cnt, N);
  deg_to_rdeg<<<(NREL * N + 255) / 256, 256, 0, stream>>>(deg, rdeg, NREL * N);

  scan1<<<nb, SCAN_B, 0, stream>>>(cnt, bsum, N);
  scan2<<<1, 128, 0, stream>>>(bsum, nb);
  scan3<<<nb, SCAN_B, 0, stream>>>(cnt, bsum, offs, cursor, N, E);
  scatter_edges<<<(E + 255) / 256, 256, 0, stream>>>(srcp, dstp, etype, rdeg, cursor, ev, E, N);

  int gblocks = (N + 63) / 64;   // 782
  gemm_mfma<IN_DIM, false><<<gblocks, 256, 0, stream>>>(x, Bt1, b1, H, AGG1, N);
  csr_agg<<<(N + 3) / 4, 256, 0, stream>>>(H, offs, ev, AGG1, N);
  gemm_mfma<HID, true><<<gblocks, 256, 0, stream>>>(AGG1, Bt2, b2, H, AGG2, N);
  csr_agg<<<(N + 3) / 4, 256, 0, stream>>>(H, offs, ev, AGG2, N);
  final_k<<<(N + 255) / 256, 256, 0, stream>>>(AGG2, Wl, bl, (float*)d_out, N);
}

// Round 4
// 332.383 us; speedup vs baseline: 1.9846x; 1.2257x over previous
//
#include <hip/hip_runtime.h>
#include <hip/hip_bf16.h>
#include <cmath>

#define IN_DIM 128
#define HID 64
#define OUT_DIM 40
#define NREL 8
#define NCOLS 576   // 8*64 (relations) + 64 (root)

typedef __attribute__((ext_vector_type(8))) short short8;
typedef __attribute__((ext_vector_type(4))) short short4v;
typedef __attribute__((ext_vector_type(4))) float floatx4;

static __device__ __forceinline__ short f2bf(float f) {
  __hip_bfloat16 h = __float2bfloat16(f);
  return __builtin_bit_cast(short, h);
}
static __device__ __forceinline__ float bf2f(short s) {
  __hip_bfloat16 h = __builtin_bit_cast(__hip_bfloat16, s);
  return __bfloat162float(h);
}

// ---- pack W[R][K][64] + root[K][64] into Bt[576][K] bf16 (K-major) ---------
__global__ void pack_bt(const float* __restrict__ W, const float* __restrict__ root,
                        short* __restrict__ Bt, int K) {
  int i = blockIdx.x * blockDim.x + threadIdx.x;
  if (i >= NCOLS * K) return;
  int c = i / K, k = i % K;
  float v;
  if (c < NREL * HID) {
    v = W[((size_t)(c >> 6) * K + k) * HID + (c & 63)];
  } else {
    v = root[(size_t)k * HID + (c - NREL * HID)];
  }
  Bt[i] = f2bf(v);
}

// ---- degree per (relation, dst) --------------------------------------------
__global__ void deg_count(const int* __restrict__ dst, const int* __restrict__ et,
                          int* __restrict__ deg, int E, int N) {
  int e = blockIdx.x * blockDim.x + threadIdx.x;
  if (e >= E) return;
  atomicAdd(&deg[(size_t)et[e] * N + dst[e]], 1);
}

__global__ void cnt_from_deg(const int* __restrict__ deg, int* __restrict__ cnt, int N) {
  int d = blockIdx.x * blockDim.x + threadIdx.x;
  if (d >= N) return;
  int s = 0;
  #pragma unroll
  for (int r = 0; r < NREL; ++r) s += deg[(size_t)r * N + d];
  cnt[d] = s;
}

__global__ void deg_to_rdeg(const int* __restrict__ deg, float* __restrict__ rdeg, int n) {
  int i = blockIdx.x * blockDim.x + threadIdx.x;
  if (i >= n) return;
  int d = deg[i];
  rdeg[i] = 1.0f / (float)(d > 1 ? d : 1);
}

// ---- exclusive scan over cnt[N] -> offs[N+1], cursor[N] --------------------
#define SCAN_B 512

__global__ void scan1(const int* __restrict__ cnt, int* __restrict__ bsum, int N) {
  __shared__ int sh[SCAN_B];
  int i = blockIdx.x * SCAN_B + threadIdx.x;
  sh[threadIdx.x] = (i < N) ? cnt[i] : 0;
  __syncthreads();
  for (int s = SCAN_B / 2; s > 0; s >>= 1) {
    if (threadIdx.x < s) sh[threadIdx.x] += sh[threadIdx.x + s];
    __syncthreads();
  }
  if (threadIdx.x == 0) bsum[blockIdx.x] = sh[0];
}

__global__ void scan2(int* __restrict__ bsum, int nb) {
  __shared__ int sh[128];
  int t = threadIdx.x;
  sh[t] = (t < nb) ? bsum[t] : 0;
  __syncthreads();
  for (int off = 1; off < 128; off <<= 1) {
    int x = sh[t];
    if (t >= off) x += sh[t - off];
    __syncthreads();
    sh[t] = x;
    __syncthreads();
  }
  if (t < nb) bsum[t] = (t == 0) ? 0 : sh[t - 1];
}

__global__ void scan3(const int* __restrict__ cnt, const int* __restrict__ bsum,
                      int* __restrict__ offs, int* __restrict__ cursor, int N, int E) {
  __shared__ int sh[SCAN_B];
  int i = blockIdx.x * SCAN_B + threadIdx.x;
  int v = (i < N) ? cnt[i] : 0;
  sh[threadIdx.x] = v;
  __syncthreads();
  for (int off = 1; off < SCAN_B; off <<= 1) {
    int x = sh[threadIdx.x];
    if (threadIdx.x >= off) x += sh[threadIdx.x - off];
    __syncthreads();
    sh[threadIdx.x] = x;
    __syncthreads();
  }
  int excl = (threadIdx.x == 0) ? 0 : sh[threadIdx.x - 1];
  int base = bsum[blockIdx.x];
  if (i < N) { offs[i] = base + excl; cursor[i] = base + excl; }
  if (i == 0) offs[N] = E;
}

// ---- scatter edges into CSR-by-dst with precomputed weight -----------------
__global__ void scatter_edges(const int* __restrict__ src, const int* __restrict__ dst,
                              const int* __restrict__ et, const float* __restrict__ rdeg,
                              int* __restrict__ cursor, int2* __restrict__ ev,
                              int E, int N) {
  int e = blockIdx.x * blockDim.x + threadIdx.x;
  if (e >= E) return;
  int d = dst[e], t = et[e];
  int pos = atomicAdd(&cursor[d], 1);
  int2 v;
  v.x = (src[e] << 3) | t;
  v.y = __float_as_int(rdeg[(size_t)t * N + d]);
  ev[pos] = v;
}

// ---- MFMA bf16 GEMM: C[M x 576] = act(A[M x K]) @ Bt^T ---------------------
template<int K, bool RELU_A>
__global__ __launch_bounds__(256, 4) void gemm_mfma(
    const float* __restrict__ A,     // [M][K] fp32
    const short* __restrict__ Bt,    // [576][K] bf16, K-major
    const float* __restrict__ bias,  // [64]
    short* __restrict__ H,           // [M][512] bf16
    float* __restrict__ AGG,         // [M][64] fp32
    int M)
{
  constexpr int AST = K + 8;
  __shared__ short As[64 * AST];
  __shared__ short Bs[64 * AST];

  int tid = threadIdx.x;
  int row0 = blockIdx.x * 64;
  int wv = tid >> 6, lane = tid & 63;
  int lm = lane & 15, quad = lane >> 4;

  constexpr int CH = K / 4;
  for (int i = tid; i < 64 * CH; i += 256) {
    int r = i / CH, kq = i % CH;
    int gr = row0 + r; if (gr >= M) gr = M - 1;
    float4 v = *(const float4*)(A + (size_t)gr * K + kq * 4);
    if (RELU_A) {
      v.x = fmaxf(v.x, 0.f); v.y = fmaxf(v.y, 0.f);
      v.z = fmaxf(v.z, 0.f); v.w = fmaxf(v.w, 0.f);
    }
    short4v s;
    s.x = f2bf(v.x); s.y = f2bf(v.y); s.z = f2bf(v.z); s.w = f2bf(v.w);
    *(short4v*)(As + r * AST + kq * 4) = s;
  }

  const short* ap = As + (16 * wv + lm) * AST + quad * 8;

  for (int cy = 0; cy < 9; ++cy) {
    constexpr int CB = K / 8;
    for (int i = tid; i < 64 * CB; i += 256) {
      int n = i / CB, ko = i % CB;
      short8 v = *(const short8*)(Bt + (size_t)(cy * 64 + n) * K + ko * 8);
      *(short8*)(Bs + n * AST + ko * 8) = v;
    }
    __syncthreads();

    floatx4 acc[4] = {{0,0,0,0},{0,0,0,0},{0,0,0,0},{0,0,0,0}};
    #pragma unroll
    for (int ks = 0; ks < K / 32; ++ks) {
      short8 a = *(const short8*)(ap + ks * 32);
      #pragma unroll
      for (int nb = 0; nb < 4; ++nb) {
        short8 b = *(const short8*)(Bs + (nb * 16 + lm) * AST + ks * 32 + quad * 8);
        acc[nb] = __builtin_amdgcn_mfma_f32_16x16x32_bf16(a, b, acc[nb], 0, 0, 0);
      }
    }
    __syncthreads();

    int mbase = row0 + 16 * wv + quad * 4;
    if (cy < 8) {
      #pragma unroll
      for (int nb = 0; nb < 4; ++nb) {
        int col = cy * 64 + nb * 16 + lm;
        #pragma unroll
        for (int r = 0; r < 4; ++r) {
          int mg = mbase + r;
          if (mg < M) H[(size_t)mg * (NREL * HID) + col] = f2bf(acc[nb][r]);
        }
      }
    } else {
      #pragma unroll
      for (int nb = 0; nb < 4; ++nb) {
        int col = nb * 16 + lm;
        float bv = bias[col];
        #pragma unroll
        for (int r = 0; r < 4; ++r) {
          int mg = mbase + r;
          if (mg < M) AGG[(size_t)mg * HID + col] = acc[nb][r] + bv;
        }
      }
    }
  }
}

// ---- CSR aggregation: one wave per dst, 8-wide batched gathers -------------
__global__ __launch_bounds__(256) void csr_agg(
    const short* __restrict__ H, const int* __restrict__ offs,
    const int2* __restrict__ ev, float* __restrict__ AGG, int N)
{
  int d = blockIdx.x * 4 + (threadIdx.x >> 6);
  if (d >= N) return;
  int lane = threadIdx.x & 63;
  int beg = offs[d], end = offs[d + 1];
  float acc = AGG[(size_t)d * HID + lane];   // root + bias part from GEMM
  if (beg < end) {
    for (int p = beg; p < end; p += 8) {
      int2 e[8];
      #pragma unroll
      for (int i = 0; i < 8; ++i) {
        int q = p + i;
        e[i] = ev[q < end ? q : (end - 1)];
      }
      short h[8];
      #pragma unroll
      for (int i = 0; i < 8; ++i) {
        int s = e[i].x >> 3, t = e[i].x & 7;
        h[i] = H[(size_t)s * (NREL * HID) + t * HID + lane];
      }
      #pragma unroll
      for (int i = 0; i < 8; ++i) {
        float w = (p + i < end) ? __int_as_float(e[i].y) : 0.f;
        acc += bf2f(h[i]) * w;
      }
    }
  }
  AGG[(size_t)d * HID + lane] = acc;
}

// ---- final: relu -> @Wl+bl -> log_softmax ----------------------------------
__global__ __launch_bounds__(256) void final_k(
    const float* __restrict__ AGG, const float* __restrict__ Wl,
    const float* __restrict__ bl, float* __restrict__ out, int N)
{
  __shared__ float sW[HID * OUT_DIM];
  __shared__ float sb[OUT_DIM];
  int tid = threadIdx.x;
  for (int i = tid; i < HID * OUT_DIM; i += 256) sW[i] = Wl[i];
  if (tid < OUT_DIM) sb[tid] = bl[tid];
  __syncthreads();

  int n = blockIdx.x * 256 + tid;
  if (n >= N) return;

  float acc[OUT_DIM];
  #pragma unroll
  for (int j = 0; j < OUT_DIM; ++j) acc[j] = sb[j];

  const float* row = AGG + (size_t)n * HID;
  for (int k = 0; k < HID; ++k) {
    float a = fmaxf(row[k], 0.f);
    #pragma unroll
    for (int j = 0; j < OUT_DIM; ++j) acc[j] += a * sW[k * OUT_DIM + j];
  }

  float m = acc[0];
  #pragma unroll
  for (int j = 1; j < OUT_DIM; ++j) m = fmaxf(m, acc[j]);
  float s = 0.f;
  #pragma unroll
  for (int j = 0; j < OUT_DIM; ++j) s += expf(acc[j] - m);
  float lse = m + logf(s);
  float* o = out + (size_t)n * OUT_DIM;
  #pragma unroll
  for (int j = 0; j < OUT_DIM; ++j) o[j] = acc[j] - lse;
}

// ---- launch ----------------------------------------------------------------
extern "C" void kernel_launch(void* const* d_in, const int* in_sizes, int n_in,
                              void* d_out, int out_size, void* d_ws, size_t ws_size,
                              hipStream_t stream) {
  const float* x     = (const float*)d_in[0];
  const int*   eidx  = (const int*)d_in[1];
  const int*   etype = (const int*)d_in[2];
  const float* W1    = (const float*)d_in[3];
  const float* root1 = (const float*)d_in[4];
  const float* b1    = (const float*)d_in[5];
  const float* W2    = (const float*)d_in[6];
  const float* root2 = (const float*)d_in[7];
  const float* b2    = (const float*)d_in[8];
  const float* Wl    = (const float*)d_in[9];
  const float* bl    = (const float*)d_in[10];

  int N = in_sizes[0] / IN_DIM;   // 50000
  int E = in_sizes[2];            // 800000
  const int* srcp = eidx;
  const int* dstp = eidx + E;

  char* ws = (char*)d_ws;
  size_t off = 0;
  auto alloc = [&](size_t bytes) -> char* {
    char* p = ws + off;
    off += (bytes + 255) & ~(size_t)255;
    return p;
  };
  short* Bt1   = (short*)alloc((size_t)NCOLS * IN_DIM * 2);
  short* Bt2   = (short*)alloc((size_t)NCOLS * HID * 2);
  int*   deg   = (int*)alloc((size_t)NREL * N * 4);
  float* rdeg  = (float*)alloc((size_t)NREL * N * 4);
  int*   cnt   = (int*)alloc((size_t)N * 4);
  int*   offs  = (int*)alloc((size_t)(N + 1) * 4);
  int*   cursor= (int*)alloc((size_t)N * 4);
  int*   bsum  = (int*)alloc(128 * 4);
  int2*  ev    = (int2*)alloc((size_t)E * 8);
  short* H     = (short*)alloc((size_t)N * NREL * HID * 2);  // 51.2 MB bf16
  float* AGG1  = (float*)alloc((size_t)N * HID * 4);
  float* AGG2  = (float*)alloc((size_t)N * HID * 4);

  int nb = (N + SCAN_B - 1) / SCAN_B;   // 98 blocks

  hipMemsetAsync(deg, 0, (size_t)NREL * N * 4, stream);
  pack_bt<<<(NCOLS * IN_DIM + 255) / 256, 256, 0, stream>>>(W1, root1, Bt1, IN_DIM);
  pack_bt<<<(NCOLS * HID + 255) / 256, 256, 0, stream>>>(W2, root2, Bt2, HID);
  deg_count<<<(E + 255) / 256, 256, 0, stream>>>(dstp, etype, deg, E, N);
  cnt_from_deg<<<(N + 255) / 256, 256, 0, stream>>>(deg, cnt, N);
  deg_to_rdeg<<<(NREL * N + 255) / 256, 256, 0, stream>>>(deg, rdeg, NREL * N);

  scan1<<<nb, SCAN_B, 0, stream>>>(cnt, bsum, N);
  scan2<<<1, 128, 0, stream>>>(bsum, nb);
  scan3<<<nb, SCAN_B, 0, stream>>>(cnt, bsum, offs, cursor, N, E);
  scatter_edges<<<(E + 255) / 256, 256, 0, stream>>>(srcp, dstp, etype, rdeg, cursor, ev, E, N);

  int gblocks = (N + 63) / 64;   // 782
  gemm_mfma<IN_DIM, false><<<gblocks, 256, 0, stream>>>(x, Bt1, b1, H, AGG1, N);
  csr_agg<<<(N + 3) / 4, 256, 0, stream>>>(H, offs, ev, AGG1, N);
  gemm_mfma<HID, true><<<gblocks, 256, 0, stream>>>(AGG1, Bt2, b2, H, AGG2, N);
  csr_agg<<<(N + 3) / 4, 256, 0, stream>>>(H, offs, ev, AGG2, N);
  final_k<<<(N + 255) / 256, 256, 0, stream>>>(AGG2, Wl, bl, (float*)d_out, N);
}

// Round 5
// 292.328 us; speedup vs baseline: 2.2565x; 1.1370x over previous
//
#include <hip/hip_runtime.h>
#include <hip/hip_bf16.h>
#include <cmath>

#define IN_DIM 128
#define HID 64
#define OUT_DIM 40
#define NREL 8
#define NCOLS 576   // 8*64 (relations) + 64 (root)

typedef __attribute__((ext_vector_type(8))) short short8;
typedef __attribute__((ext_vector_type(4))) short short4v;
typedef __attribute__((ext_vector_type(4))) float floatx4;

static __device__ __forceinline__ short f2bf(float f) {
  __hip_bfloat16 h = __float2bfloat16(f);
  return __builtin_bit_cast(short, h);
}

// ---- pack W[R][K][64] + root[K][64] into Bt[576][K] bf16 (K-major) ---------
__global__ void pack_bt(const float* __restrict__ W, const float* __restrict__ root,
                        short* __restrict__ Bt, int K) {
  int i = blockIdx.x * blockDim.x + threadIdx.x;
  if (i >= NCOLS * K) return;
  int c = i / K, k = i % K;
  float v;
  if (c < NREL * HID) {
    v = W[((size_t)(c >> 6) * K + k) * HID + (c & 63)];
  } else {
    v = root[(size_t)k * HID + (c - NREL * HID)];
  }
  Bt[i] = f2bf(v);
}

// ---- degree per (relation, dst) --------------------------------------------
__global__ void deg_count(const int* __restrict__ dst, const int* __restrict__ et,
                          int* __restrict__ deg, int E, int N) {
  int e = blockIdx.x * blockDim.x + threadIdx.x;
  if (e >= E) return;
  atomicAdd(&deg[(size_t)et[e] * N + dst[e]], 1);
}

// ---- cnt[d] = total in-degree; rdeg = 1/max(deg,1) -------------------------
__global__ void cnt_rdeg(const int* __restrict__ deg, int* __restrict__ cnt,
                         float* __restrict__ rdeg, int N) {
  int d = blockIdx.x * blockDim.x + threadIdx.x;
  if (d >= N) return;
  int s = 0;
  #pragma unroll
  for (int r = 0; r < NREL; ++r) {
    int dv = deg[(size_t)r * N + d];
    s += dv;
    rdeg[(size_t)r * N + d] = 1.0f / (float)(dv > 1 ? dv : 1);
  }
  cnt[d] = s;
}

// ---- exclusive scan over cnt[N] -> offs[N+1], cursor[N] --------------------
#define SCAN_B 512

__global__ void scan1(const int* __restrict__ cnt, int* __restrict__ bsum, int N) {
  __shared__ int sh[SCAN_B];
  int i = blockIdx.x * SCAN_B + threadIdx.x;
  sh[threadIdx.x] = (i < N) ? cnt[i] : 0;
  __syncthreads();
  for (int s = SCAN_B / 2; s > 0; s >>= 1) {
    if (threadIdx.x < s) sh[threadIdx.x] += sh[threadIdx.x + s];
    __syncthreads();
  }
  if (threadIdx.x == 0) bsum[blockIdx.x] = sh[0];
}

__global__ void scan2(int* __restrict__ bsum, int nb) {
  __shared__ int sh[128];
  int t = threadIdx.x;
  sh[t] = (t < nb) ? bsum[t] : 0;
  __syncthreads();
  for (int off = 1; off < 128; off <<= 1) {
    int x = sh[t];
    if (t >= off) x += sh[t - off];
    __syncthreads();
    sh[t] = x;
    __syncthreads();
  }
  if (t < nb) bsum[t] = (t == 0) ? 0 : sh[t - 1];
}

__global__ void scan3(const int* __restrict__ cnt, const int* __restrict__ bsum,
                      int* __restrict__ offs, int* __restrict__ cursor, int N, int E) {
  __shared__ int sh[SCAN_B];
  int i = blockIdx.x * SCAN_B + threadIdx.x;
  int v = (i < N) ? cnt[i] : 0;
  sh[threadIdx.x] = v;
  __syncthreads();
  for (int off = 1; off < SCAN_B; off <<= 1) {
    int x = sh[threadIdx.x];
    if (threadIdx.x >= off) x += sh[threadIdx.x - off];
    __syncthreads();
    sh[threadIdx.x] = x;
    __syncthreads();
  }
  int excl = (threadIdx.x == 0) ? 0 : sh[threadIdx.x - 1];
  int base = bsum[blockIdx.x];
  if (i < N) { offs[i] = base + excl; cursor[i] = base + excl; }
  if (i == 0) offs[N] = E;
}

// ---- shared MFMA GEMM body: C[64 x 576] = act(A tile) @ Bt^T ---------------
// cols 0..511 -> H (bf16); cols 512..575 -> AGG (fp32, +bias)
template<int K, bool RELU_A>
__device__ __forceinline__ void gemm_dev(
    short* As, short* Bs,
    const float* __restrict__ A, const short* __restrict__ Bt,
    const float* __restrict__ bias, short* __restrict__ H,
    float* __restrict__ AGG, int M, int row0)
{
  constexpr int AST = K + 8;
  int tid = threadIdx.x;
  int wv = tid >> 6, lane = tid & 63;
  int lm = lane & 15, quad = lane >> 4;

  constexpr int CH = K / 4;
  for (int i = tid; i < 64 * CH; i += 256) {
    int r = i / CH, kq = i % CH;
    int gr = row0 + r; if (gr >= M) gr = M - 1;
    float4 v = *(const float4*)(A + (size_t)gr * K + kq * 4);
    if (RELU_A) {
      v.x = fmaxf(v.x, 0.f); v.y = fmaxf(v.y, 0.f);
      v.z = fmaxf(v.z, 0.f); v.w = fmaxf(v.w, 0.f);
    }
    short4v s;
    s.x = f2bf(v.x); s.y = f2bf(v.y); s.z = f2bf(v.z); s.w = f2bf(v.w);
    *(short4v*)(As + r * AST + kq * 4) = s;
  }

  const short* ap = As + (16 * wv + lm) * AST + quad * 8;

  for (int cy = 0; cy < 9; ++cy) {
    constexpr int CB = K / 8;
    for (int i = tid; i < 64 * CB; i += 256) {
      int n = i / CB, ko = i % CB;
      short8 v = *(const short8*)(Bt + (size_t)(cy * 64 + n) * K + ko * 8);
      *(short8*)(Bs + n * AST + ko * 8) = v;
    }
    __syncthreads();

    floatx4 acc[4] = {{0,0,0,0},{0,0,0,0},{0,0,0,0},{0,0,0,0}};
    #pragma unroll
    for (int ks = 0; ks < K / 32; ++ks) {
      short8 a = *(const short8*)(ap + ks * 32);
      #pragma unroll
      for (int nb = 0; nb < 4; ++nb) {
        short8 b = *(const short8*)(Bs + (nb * 16 + lm) * AST + ks * 32 + quad * 8);
        acc[nb] = __builtin_amdgcn_mfma_f32_16x16x32_bf16(a, b, acc[nb], 0, 0, 0);
      }
    }
    __syncthreads();

    int mbase = row0 + 16 * wv + quad * 4;
    if (cy < 8) {
      #pragma unroll
      for (int nb = 0; nb < 4; ++nb) {
        int col = cy * 64 + nb * 16 + lm;
        #pragma unroll
        for (int r = 0; r < 4; ++r) {
          int mg = mbase + r;
          if (mg < M) H[(size_t)mg * (NREL * HID) + col] = f2bf(acc[nb][r]);
        }
      }
    } else {
      #pragma unroll
      for (int nb = 0; nb < 4; ++nb) {
        int col = nb * 16 + lm;
        float bv = bias[col];
        #pragma unroll
        for (int r = 0; r < 4; ++r) {
          int mg = mbase + r;
          if (mg < M) AGG[(size_t)mg * HID + col] = acc[nb][r] + bv;
        }
      }
    }
  }
}

// ---- fused: gemm layer-1 (blocks < GB) + edge scatter (blocks >= GB) -------
__global__ __launch_bounds__(256, 4) void gemm1_scatter(
    const float* __restrict__ A, const short* __restrict__ Bt,
    const float* __restrict__ bias, short* __restrict__ H,
    float* __restrict__ AGG, int M, int GB,
    const int* __restrict__ src, const int* __restrict__ dst,
    const int* __restrict__ et, const float* __restrict__ rdeg,
    int* __restrict__ cursor, int2* __restrict__ ev, int E, int N)
{
  constexpr int AST = IN_DIM + 8;
  __shared__ short As[64 * AST];
  __shared__ short Bs[64 * AST];
  if ((int)blockIdx.x < GB) {
    gemm_dev<IN_DIM, false>(As, Bs, A, Bt, bias, H, AGG, M, blockIdx.x * 64);
  } else {
    int e = (blockIdx.x - GB) * 256 + threadIdx.x;
    if (e >= E) return;
    int d = dst[e], t = et[e];
    int pos = atomicAdd(&cursor[d], 1);
    int2 v;
    v.x = (src[e] << 3) | t;
    v.y = __float_as_int(rdeg[(size_t)t * N + d]);
    ev[pos] = v;
  }
}

// ---- standalone gemm (layer 2) ---------------------------------------------
template<int K, bool RELU_A>
__global__ __launch_bounds__(256, 4) void gemm_mfma(
    const float* __restrict__ A, const short* __restrict__ Bt,
    const float* __restrict__ bias, short* __restrict__ H,
    float* __restrict__ AGG, int M)
{
  constexpr int AST = K + 8;
  __shared__ short As[64 * AST];
  __shared__ short Bs[64 * AST];
  gemm_dev<K, RELU_A>(As, Bs, A, Bt, bias, H, AGG, M, blockIdx.x * 64);
}

// ---- CSR aggregation core: half-wave split gather, 2 edges per wave-iter ---
// lanes 0-31 stream edges p..p+7, lanes 32-63 stream p+8..p+15; each lane
// holds dims (2*sub, 2*sub+1) as one uint (2 bf16). Returns combined acc in
// half 0 lanes.
static __device__ __forceinline__ void csr_core(
    const unsigned int* __restrict__ Hu, const int2* __restrict__ ev,
    int beg, int end, int half, int sub, float& a0, float& a1)
{
  for (int p = beg; p < end; p += 16) {
    int2 e[8];
    #pragma unroll
    for (int i = 0; i < 8; ++i) {
      int q = p + 8 * half + i;
      e[i] = ev[q < end ? q : (end - 1)];
    }
    unsigned int hv[8];
    #pragma unroll
    for (int i = 0; i < 8; ++i) {
      int s = e[i].x >> 3, t = e[i].x & 7;
      hv[i] = Hu[(size_t)s * 256 + t * 32 + sub];
    }
    #pragma unroll
    for (int i = 0; i < 8; ++i) {
      float w = (p + 8 * half + i < end) ? __int_as_float(e[i].y) : 0.f;
      float lo = __int_as_float(hv[i] << 16);
      float hi = __int_as_float(hv[i] & 0xffff0000u);
      a0 += lo * w;
      a1 += hi * w;
    }
  }
  a0 += __shfl_down(a0, 32, 64);
  a1 += __shfl_down(a1, 32, 64);
}

// ---- layer-1 aggregation: AGG += mean-messages ------------------------------
__global__ __launch_bounds__(256) void csr_agg(
    const short* __restrict__ H, const int* __restrict__ offs,
    const int2* __restrict__ ev, float* __restrict__ AGG, int N)
{
  int d = blockIdx.x * 4 + (threadIdx.x >> 6);
  if (d >= N) return;
  int lane = threadIdx.x & 63;
  int half = lane >> 5, sub = lane & 31;
  int beg = offs[d], end = offs[d + 1];
  float a0 = 0.f, a1 = 0.f;
  if (half == 0) {
    float2 v = *(const float2*)(AGG + (size_t)d * HID + sub * 2);
    a0 = v.x; a1 = v.y;
  }
  csr_core((const unsigned int*)H, ev, beg, end, half, sub, a0, a1);
  if (half == 0) {
    float2 v; v.x = a0; v.y = a1;
    *(float2*)(AGG + (size_t)d * HID + sub * 2) = v;
  }
}

// ---- layer-2 aggregation fused with relu -> @Wl+bl -> log_softmax ----------
__global__ __launch_bounds__(256) void csr_agg_final(
    const short* __restrict__ H, const int* __restrict__ offs,
    const int2* __restrict__ ev, const float* __restrict__ AGG,
    const float* __restrict__ Wl, const float* __restrict__ bl,
    float* __restrict__ out, int N)
{
  __shared__ float sWl[HID * OUT_DIM];
  __shared__ float sbl[OUT_DIM];
  __shared__ float sh[4][HID];
  int tid = threadIdx.x;
  for (int i = tid; i < HID * OUT_DIM; i += 256) sWl[i] = Wl[i];
  if (tid < OUT_DIM) sbl[tid] = bl[tid];
  __syncthreads();

  int wv = tid >> 6, lane = tid & 63;
  int half = lane >> 5, sub = lane & 31;
  int d = blockIdx.x * 4 + wv;
  bool valid = d < N;
  int dc = valid ? d : (N - 1);

  int beg = offs[dc], end = offs[dc + 1];
  float a0 = 0.f, a1 = 0.f;
  if (half == 0) {
    float2 v = *(const float2*)(AGG + (size_t)dc * HID + sub * 2);
    a0 = v.x; a1 = v.y;
  }
  csr_core((const unsigned int*)H, ev, beg, end, half, sub, a0, a1);
  if (half == 0) {
    sh[wv][2 * sub]     = fmaxf(a0, 0.f);
    sh[wv][2 * sub + 1] = fmaxf(a1, 0.f);
  }
  __syncthreads();

  float logit = -__builtin_inff();
  if (lane < OUT_DIM) {
    float t = sbl[lane];
    #pragma unroll 8
    for (int k = 0; k < HID; ++k) t += sh[wv][k] * sWl[k * OUT_DIM + lane];
    logit = t;
  }
  float m = logit;
  #pragma unroll
  for (int o = 32; o > 0; o >>= 1) m = fmaxf(m, __shfl_xor(m, o, 64));
  float ex = (lane < OUT_DIM) ? expf(logit - m) : 0.f;
  float s = ex;
  #pragma unroll
  for (int o = 32; o > 0; o >>= 1) s += __shfl_xor(s, o, 64);
  if (valid && lane < OUT_DIM)
    out[(size_t)d * OUT_DIM + lane] = logit - m - logf(s);
}

// ---- launch ----------------------------------------------------------------
extern "C" void kernel_launch(void* const* d_in, const int* in_sizes, int n_in,
                              void* d_out, int out_size, void* d_ws, size_t ws_size,
                              hipStream_t stream) {
  const float* x     = (const float*)d_in[0];
  const int*   eidx  = (const int*)d_in[1];
  const int*   etype = (const int*)d_in[2];
  const float* W1    = (const float*)d_in[3];
  const float* root1 = (const float*)d_in[4];
  const float* b1    = (const float*)d_in[5];
  const float* W2    = (const float*)d_in[6];
  const float* root2 = (const float*)d_in[7];
  const float* b2    = (const float*)d_in[8];
  const float* Wl    = (const float*)d_in[9];
  const float* bl    = (const float*)d_in[10];

  int N = in_sizes[0] / IN_DIM;   // 50000
  int E = in_sizes[2];            // 800000
  const int* srcp = eidx;
  const int* dstp = eidx + E;

  char* ws = (char*)d_ws;
  size_t off = 0;
  auto alloc = [&](size_t bytes) -> char* {
    char* p = ws + off;
    off += (bytes + 255) & ~(size_t)255;
    return p;
  };
  short* Bt1   = (short*)alloc((size_t)NCOLS * IN_DIM * 2);
  short* Bt2   = (short*)alloc((size_t)NCOLS * HID * 2);
  int*   deg   = (int*)alloc((size_t)NREL * N * 4);
  float* rdeg  = (float*)alloc((size_t)NREL * N * 4);
  int*   cnt   = (int*)alloc((size_t)N * 4);
  int*   offs  = (int*)alloc((size_t)(N + 1) * 4);
  int*   cursor= (int*)alloc((size_t)N * 4);
  int*   bsum  = (int*)alloc(128 * 4);
  int2*  ev    = (int2*)alloc((size_t)E * 8);
  short* H     = (short*)alloc((size_t)N * NREL * HID * 2);  // 51.2 MB bf16
  float* AGG1  = (float*)alloc((size_t)N * HID * 4);
  float* AGG2  = (float*)alloc((size_t)N * HID * 4);

  int nb = (N + SCAN_B - 1) / SCAN_B;   // 98 blocks

  hipMemsetAsync(deg, 0, (size_t)NREL * N * 4, stream);
  pack_bt<<<(NCOLS * IN_DIM + 255) / 256, 256, 0, stream>>>(W1, root1, Bt1, IN_DIM);
  pack_bt<<<(NCOLS * HID + 255) / 256, 256, 0, stream>>>(W2, root2, Bt2, HID);
  deg_count<<<(E + 255) / 256, 256, 0, stream>>>(dstp, etype, deg, E, N);
  cnt_rdeg<<<(N + 255) / 256, 256, 0, stream>>>(deg, cnt, rdeg, N);

  scan1<<<nb, SCAN_B, 0, stream>>>(cnt, bsum, N);
  scan2<<<1, 128, 0, stream>>>(bsum, nb);
  scan3<<<nb, SCAN_B, 0, stream>>>(cnt, bsum, offs, cursor, N, E);

  int GB = (N + 63) / 64;        // 782 gemm blocks
  int SB = (E + 255) / 256;      // 3125 scatter blocks
  gemm1_scatter<<<GB + SB, 256, 0, stream>>>(x, Bt1, b1, H, AGG1, N, GB,
                                             srcp, dstp, etype, rdeg, cursor, ev, E, N);
  csr_agg<<<(N + 3) / 4, 256, 0, stream>>>(H, offs, ev, AGG1, N);
  gemm_mfma<HID, true><<<GB, 256, 0, stream>>>(AGG1, Bt2, b2, H, AGG2, N);
  csr_agg_final<<<(N + 3) / 4, 256, 0, stream>>>(H, offs, ev, AGG2, Wl, bl,
                                                 (float*)d_out, N);
}

// Round 7
// 274.912 us; speedup vs baseline: 2.3995x; 1.0634x over previous
//
#include <hip/hip_runtime.h>
#include <hip/hip_bf16.h>
#include <cmath>

#define IN_DIM 128
#define HID 64
#define OUT_DIM 40
#define NREL 8
#define NCOLS 576   // 8*64 (relations) + 64 (root)

typedef __attribute__((ext_vector_type(8))) short short8;
typedef __attribute__((ext_vector_type(4))) short short4v;
typedef __attribute__((ext_vector_type(4))) float floatx4;

static __device__ __forceinline__ short f2bf(float f) {
  __hip_bfloat16 h = __float2bfloat16(f);
  return __builtin_bit_cast(short, h);
}
static __device__ __forceinline__ float bflo(unsigned int u) {
  return __int_as_float(u << 16);
}
static __device__ __forceinline__ float bfhi(unsigned int u) {
  return __int_as_float(u & 0xffff0000u);
}
static __device__ __forceinline__ unsigned int packbf(float x, float y) {
  unsigned int lo = (unsigned short)f2bf(x);
  unsigned int hi = (unsigned short)f2bf(y);
  return lo | (hi << 16);
}

// ---- fused prep: pack Bt1, pack Bt2, per-(dst,rel) degree histogram --------
__global__ void prep(const float* __restrict__ W1, const float* __restrict__ root1,
                     short* __restrict__ Bt1,
                     const float* __restrict__ W2, const float* __restrict__ root2,
                     short* __restrict__ Bt2,
                     const int* __restrict__ dst, const int* __restrict__ et,
                     int* __restrict__ deg8, int E) {
  const int PB1 = (NCOLS * IN_DIM + 255) / 256;   // 288
  const int PB2 = (NCOLS * HID + 255) / 256;      // 144
  int b = blockIdx.x;
  if (b < PB1) {
    int i = b * 256 + threadIdx.x;
    if (i >= NCOLS * IN_DIM) return;
    int c = i / IN_DIM, k = i % IN_DIM;
    float v = (c < NREL * HID)
      ? W1[((size_t)(c >> 6) * IN_DIM + k) * HID + (c & 63)]
      : root1[(size_t)k * HID + (c - NREL * HID)];
    Bt1[i] = f2bf(v);
  } else if (b < PB1 + PB2) {
    int i = (b - PB1) * 256 + threadIdx.x;
    if (i >= NCOLS * HID) return;
    int c = i / HID, k = i % HID;
    float v = (c < NREL * HID)
      ? W2[((size_t)(c >> 6) * HID + k) * HID + (c & 63)]
      : root2[(size_t)k * HID + (c - NREL * HID)];
    Bt2[i] = f2bf(v);
  } else {
    int e = (b - PB1 - PB2) * 256 + threadIdx.x;
    if (e >= E) return;
    atomicAdd(&deg8[(size_t)dst[e] * 8 + et[e]], 1);
  }
}

// ---- fused: rdeg8 + per-node count + block partial sums (scan phase 1) -----
#define SCAN_B 512

__global__ void cnt_scan(const int* __restrict__ deg8, float* __restrict__ rdeg8,
                         int* __restrict__ cnt, int* __restrict__ bsum, int N) {
  __shared__ int sh[SCAN_B];
  int i = blockIdx.x * SCAN_B + threadIdx.x;
  int s = 0;
  if (i < N) {
    int4 d0 = *(const int4*)(deg8 + (size_t)i * 8);
    int4 d1 = *(const int4*)(deg8 + (size_t)i * 8 + 4);
    s = d0.x + d0.y + d0.z + d0.w + d1.x + d1.y + d1.z + d1.w;
    float4 r0, r1;
    r0.x = 1.0f / (float)(d0.x > 1 ? d0.x : 1);
    r0.y = 1.0f / (float)(d0.y > 1 ? d0.y : 1);
    r0.z = 1.0f / (float)(d0.z > 1 ? d0.z : 1);
    r0.w = 1.0f / (float)(d0.w > 1 ? d0.w : 1);
    r1.x = 1.0f / (float)(d1.x > 1 ? d1.x : 1);
    r1.y = 1.0f / (float)(d1.y > 1 ? d1.y : 1);
    r1.z = 1.0f / (float)(d1.z > 1 ? d1.z : 1);
    r1.w = 1.0f / (float)(d1.w > 1 ? d1.w : 1);
    *(float4*)(rdeg8 + (size_t)i * 8) = r0;
    *(float4*)(rdeg8 + (size_t)i * 8 + 4) = r1;
    cnt[i] = s;
  }
  sh[threadIdx.x] = s;
  __syncthreads();
  for (int st = SCAN_B / 2; st > 0; st >>= 1) {
    if (threadIdx.x < st) sh[threadIdx.x] += sh[threadIdx.x + st];
    __syncthreads();
  }
  if (threadIdx.x == 0) bsum[blockIdx.x] = sh[0];
}

__global__ void scan2(int* __restrict__ bsum, int nb) {
  __shared__ int sh[128];
  int t = threadIdx.x;
  sh[t] = (t < nb) ? bsum[t] : 0;
  __syncthreads();
  for (int off = 1; off < 128; off <<= 1) {
    int x = sh[t];
    if (t >= off) x += sh[t - off];
    __syncthreads();
    sh[t] = x;
    __syncthreads();
  }
  if (t < nb) bsum[t] = (t == 0) ? 0 : sh[t - 1];
}

__global__ void scan3(const int* __restrict__ cnt, const int* __restrict__ bsum,
                      int* __restrict__ offs, int* __restrict__ cursor, int N, int E) {
  __shared__ int sh[SCAN_B];
  int i = blockIdx.x * SCAN_B + threadIdx.x;
  int v = (i < N) ? cnt[i] : 0;
  sh[threadIdx.x] = v;
  __syncthreads();
  for (int off = 1; off < SCAN_B; off <<= 1) {
    int x = sh[threadIdx.x];
    if (threadIdx.x >= off) x += sh[threadIdx.x - off];
    __syncthreads();
    sh[threadIdx.x] = x;
    __syncthreads();
  }
  int excl = (threadIdx.x == 0) ? 0 : sh[threadIdx.x - 1];
  int base = bsum[blockIdx.x];
  if (i < N) { offs[i] = base + excl; cursor[i] = base + excl; }
  if (i == 0) offs[N] = E;
}

// ---- shared MFMA GEMM body: C[64 x 576] = act(A tile) @ Bt^T ---------------
// AMODE 0: A fp32, no relu.  AMODE 1: A bf16, relu.
// cols 0..511 -> H (bf16); cols 512..575 -> AGG (bf16, +bias)
template<int K, int AMODE>
__device__ __forceinline__ void gemm_dev(
    short* As, short* Bs,
    const void* __restrict__ Aptr, const short* __restrict__ Bt,
    const float* __restrict__ bias, short* __restrict__ H,
    unsigned short* __restrict__ AGG, int M, int row0)
{
  constexpr int AST = K + 8;
  int tid = threadIdx.x;
  int wv = tid >> 6, lane = tid & 63;
  int lm = lane & 15, quad = lane >> 4;

  if (AMODE == 0) {
    const float* A = (const float*)Aptr;
    constexpr int CH = K / 4;
    for (int i = tid; i < 64 * CH; i += 256) {
      int r = i / CH, kq = i % CH;
      int gr = row0 + r; if (gr >= M) gr = M - 1;
      float4 v = *(const float4*)(A + (size_t)gr * K + kq * 4);
      short4v s;
      s.x = f2bf(v.x); s.y = f2bf(v.y); s.z = f2bf(v.z); s.w = f2bf(v.w);
      *(short4v*)(As + r * AST + kq * 4) = s;
    }
  } else {
    const short* A = (const short*)Aptr;
    constexpr int CH = K / 8;
    for (int i = tid; i < 64 * CH; i += 256) {
      int r = i / CH, ko = i % CH;
      int gr = row0 + r; if (gr >= M) gr = M - 1;
      short8 v = *(const short8*)(A + (size_t)gr * K + ko * 8);
      #pragma unroll
      for (int j = 0; j < 8; ++j)
        if ((unsigned short)v[j] & 0x8000u) v[j] = 0;   // bf16 relu
      *(short8*)(As + r * AST + ko * 8) = v;
    }
  }

  const short* ap = As + (16 * wv + lm) * AST + quad * 8;

  for (int cy = 0; cy < 9; ++cy) {
    constexpr int CB = K / 8;
    for (int i = tid; i < 64 * CB; i += 256) {
      int n = i / CB, ko = i % CB;
      short8 v = *(const short8*)(Bt + (size_t)(cy * 64 + n) * K + ko * 8);
      *(short8*)(Bs + n * AST + ko * 8) = v;
    }
    __syncthreads();

    floatx4 acc[4] = {{0,0,0,0},{0,0,0,0},{0,0,0,0},{0,0,0,0}};
    #pragma unroll
    for (int ks = 0; ks < K / 32; ++ks) {
      short8 a = *(const short8*)(ap + ks * 32);
      #pragma unroll
      for (int nb = 0; nb < 4; ++nb) {
        short8 b = *(const short8*)(Bs + (nb * 16 + lm) * AST + ks * 32 + quad * 8);
        acc[nb] = __builtin_amdgcn_mfma_f32_16x16x32_bf16(a, b, acc[nb], 0, 0, 0);
      }
    }
    __syncthreads();

    int mbase = row0 + 16 * wv + quad * 4;
    if (cy < 8) {
      #pragma unroll
      for (int nb = 0; nb < 4; ++nb) {
        int col = cy * 64 + nb * 16 + lm;
        #pragma unroll
        for (int r = 0; r < 4; ++r) {
          int mg = mbase + r;
          if (mg < M) H[(size_t)mg * (NREL * HID) + col] = f2bf(acc[nb][r]);
        }
      }
    } else {
      #pragma unroll
      for (int nb = 0; nb < 4; ++nb) {
        int col = nb * 16 + lm;
        float bv = bias[col];
        #pragma unroll
        for (int r = 0; r < 4; ++r) {
          int mg = mbase + r;
          if (mg < M)
            AGG[(size_t)mg * HID + col] = (unsigned short)f2bf(acc[nb][r] + bv);
        }
      }
    }
  }
}

// ---- fused: gemm layer-1 (blocks < GB) + edge scatter (blocks >= GB) -------
__global__ __launch_bounds__(256, 4) void gemm1_scatter(
    const float* __restrict__ A, const short* __restrict__ Bt,
    const float* __restrict__ bias, short* __restrict__ H,
    unsigned short* __restrict__ AGG, int M, int GB,
    const int* __restrict__ src, const int* __restrict__ dst,
    const int* __restrict__ et,
    int* __restrict__ cursor, int* __restrict__ ev, int E)
{
  constexpr int AST = IN_DIM + 8;
  __shared__ short As[64 * AST];
  __shared__ short Bs[64 * AST];
  if ((int)blockIdx.x < GB) {
    gemm_dev<IN_DIM, 0>(As, Bs, A, Bt, bias, H, AGG, M, blockIdx.x * 64);
  } else {
    int e = (blockIdx.x - GB) * 256 + threadIdx.x;
    if (e >= E) return;
    int d = dst[e];
    int pos = atomicAdd(&cursor[d], 1);
    __builtin_nontemporal_store((src[e] << 3) | et[e], &ev[pos]);
  }
}

// ---- standalone gemm (layer 2, bf16 A with relu) ---------------------------
__global__ __launch_bounds__(256, 4) void gemm2_mfma(
    const unsigned short* __restrict__ A, const short* __restrict__ Bt,
    const float* __restrict__ bias, short* __restrict__ H,
    unsigned short* __restrict__ AGG, int M)
{
  constexpr int AST = HID + 8;
  __shared__ short As[64 * AST];
  __shared__ short Bs[64 * AST];
  gemm_dev<HID, 1>(As, Bs, A, Bt, bias, H, AGG, M, blockIdx.x * 64);
}

// ---- CSR aggregation core: quarter-wave, uint2 (4 bf16 dims) per lane ------
// quarter q streams edges p+8q..p+8q+7; lane sub holds dims 4sub..4sub+3.
// H row (s,t) = bf16 offset 64*e  =>  uint2 offset 16*e  (e = s*8+t).
// Weight resolved by shfl from lanes 0..7 holding rdeg8[d][0..7].
static __device__ __forceinline__ void csr_core(
    const uint2* __restrict__ Hu2, const int* __restrict__ ev,
    int beg, int end, int q, int sub, float rv,
    float& a0, float& a1, float& a2, float& a3)
{
  for (int p = beg; p < end; p += 32) {
    int e[8];
    #pragma unroll
    for (int i = 0; i < 8; ++i) {
      int idx = p + 8 * q + i;
      e[i] = ev[idx < end ? idx : end - 1];
    }
    uint2 hv[8];
    #pragma unroll
    for (int i = 0; i < 8; ++i)
      hv[i] = Hu2[(size_t)e[i] * 16 + sub];
    #pragma unroll
    for (int i = 0; i < 8; ++i) {
      float wt = __shfl(rv, e[i] & 7, 64);
      if (p + 8 * q + i >= end) wt = 0.f;
      a0 += bflo(hv[i].x) * wt;
      a1 += bfhi(hv[i].x) * wt;
      a2 += bflo(hv[i].y) * wt;
      a3 += bfhi(hv[i].y) * wt;
    }
  }
  a0 += __shfl_xor(a0, 16, 64); a0 += __shfl_xor(a0, 32, 64);
  a1 += __shfl_xor(a1, 16, 64); a1 += __shfl_xor(a1, 32, 64);
  a2 += __shfl_xor(a2, 16, 64); a2 += __shfl_xor(a2, 32, 64);
  a3 += __shfl_xor(a3, 16, 64); a3 += __shfl_xor(a3, 32, 64);
}

// ---- layer-1 aggregation: AGG(bf16) += mean-messages -----------------------
__global__ __launch_bounds__(256) void csr_agg(
    const short* __restrict__ H, const int* __restrict__ offs,
    const int* __restrict__ ev, const float* __restrict__ rdeg8,
    unsigned short* __restrict__ AGG, int N)
{
  int d = blockIdx.x * 4 + (threadIdx.x >> 6);
  if (d >= N) return;
  int lane = threadIdx.x & 63;
  int q = lane >> 4, sub = lane & 15;
  float rv = (lane < 8) ? rdeg8[(size_t)d * 8 + lane] : 0.f;
  int beg = offs[d], end = offs[d + 1];
  float a0 = 0.f, a1 = 0.f, a2 = 0.f, a3 = 0.f;
  uint2* aggrow = (uint2*)(AGG + (size_t)d * HID);
  if (q == 0) {
    uint2 iv = aggrow[sub];
    a0 = bflo(iv.x); a1 = bfhi(iv.x); a2 = bflo(iv.y); a3 = bfhi(iv.y);
  }
  csr_core((const uint2*)H, ev, beg, end, q, sub, rv, a0, a1, a2, a3);
  if (q == 0) {
    uint2 ov;
    ov.x = packbf(a0, a1);
    ov.y = packbf(a2, a3);
    aggrow[sub] = ov;
  }
}

// ---- layer-2 aggregation fused with relu -> @Wl+bl -> log_softmax ----------
__global__ __launch_bounds__(256) void csr_agg_final(
    const short* __restrict__ H, const int* __restrict__ offs,
    const int* __restrict__ ev, const float* __restrict__ rdeg8,
    const unsigned short* __restrict__ AGG,
    const float* __restrict__ Wl, const float* __restrict__ bl,
    float* __restrict__ out, int N)
{
  __shared__ float sWl[HID * OUT_DIM];
  __shared__ float sbl[OUT_DIM];
  __shared__ float sh[4][HID];
  int tid = threadIdx.x;
  for (int i = tid; i < HID * OUT_DIM; i += 256) sWl[i] = Wl[i];
  if (tid < OUT_DIM) sbl[tid] = bl[tid];
  __syncthreads();

  int wv = tid >> 6, lane = tid & 63;
  int q = lane >> 4, sub = lane & 15;
  int d = blockIdx.x * 4 + wv;
  bool valid = d < N;
  int dc = valid ? d : (N - 1);

  float rv = (lane < 8) ? rdeg8[(size_t)dc * 8 + lane] : 0.f;
  int beg = offs[dc], end = offs[dc + 1];
  float a0 = 0.f, a1 = 0.f, a2 = 0.f, a3 = 0.f;
  if (q == 0) {
    uint2 iv = ((const uint2*)(AGG + (size_t)dc * HID))[sub];
    a0 = bflo(iv.x); a1 = bfhi(iv.x); a2 = bflo(iv.y); a3 = bfhi(iv.y);
  }
  csr_core((const uint2*)H, ev, beg, end, q, sub, rv, a0, a1, a2, a3);
  if (q == 0) {
    float4 v;
    v.x = fmaxf(a0, 0.f); v.y = fmaxf(a1, 0.f);
    v.z = fmaxf(a2, 0.f); v.w = fmaxf(a3, 0.f);
    *(float4*)(&sh[wv][4 * sub]) = v;
  }
  __syncthreads();

  float logit = -__builtin_inff();
  if (lane < OUT_DIM) {
    float t = sbl[lane];
    #pragma unroll 8
    for (int k = 0; k < HID; ++k) t += sh[wv][k] * sWl[k * OUT_DIM + lane];
    logit = t;
  }
  float m = logit;
  #pragma unroll
  for (int o = 32; o > 0; o >>= 1) m = fmaxf(m, __shfl_xor(m, o, 64));
  float ex = (lane < OUT_DIM) ? expf(logit - m) : 0.f;
  float s = ex;
  #pragma unroll
  for (int o = 32; o > 0; o >>= 1) s += __shfl_xor(s, o, 64);
  if (valid && lane < OUT_DIM)
    out[(size_t)d * OUT_DIM + lane] = logit - m - logf(s);
}

// ---- launch ----------------------------------------------------------------
extern "C" void kernel_launch(void* const* d_in, const int* in_sizes, int n_in,
                              void* d_out, int out_size, void* d_ws, size_t ws_size,
                              hipStream_t stream) {
  const float* x     = (const float*)d_in[0];
  const int*   eidx  = (const int*)d_in[1];
  const int*   etype = (const int*)d_in[2];
  const float* W1    = (const float*)d_in[3];
  const float* root1 = (const float*)d_in[4];
  const float* b1    = (const float*)d_in[5];
  const float* W2    = (const float*)d_in[6];
  const float* root2 = (const float*)d_in[7];
  const float* b2    = (const float*)d_in[8];
  const float* Wl    = (const float*)d_in[9];
  const float* bl    = (const float*)d_in[10];

  int N = in_sizes[0] / IN_DIM;   // 50000
  int E = in_sizes[2];            // 800000
  const int* srcp = eidx;
  const int* dstp = eidx + E;

  char* ws = (char*)d_ws;
  size_t off = 0;
  auto alloc = [&](size_t bytes) -> char* {
    char* p = ws + off;
    off += (bytes + 255) & ~(size_t)255;
    return p;
  };
  short* Bt1    = (short*)alloc((size_t)NCOLS * IN_DIM * 2);
  short* Bt2    = (short*)alloc((size_t)NCOLS * HID * 2);
  int*   deg8   = (int*)alloc((size_t)N * 8 * 4);
  float* rdeg8  = (float*)alloc((size_t)N * 8 * 4);
  int*   cnt    = (int*)alloc((size_t)N * 4);
  int*   offs   = (int*)alloc((size_t)(N + 1) * 4);
  int*   cursor = (int*)alloc((size_t)N * 4);
  int*   bsum   = (int*)alloc(128 * 4);
  int*   ev     = (int*)alloc((size_t)E * 4);
  short* H      = (short*)alloc((size_t)N * NREL * HID * 2);  // 51.2 MB bf16
  unsigned short* AGG1 = (unsigned short*)alloc((size_t)N * HID * 2);
  unsigned short* AGG2 = (unsigned short*)alloc((size_t)N * HID * 2);

  int nb = (N + SCAN_B - 1) / SCAN_B;   // 98 blocks

  hipMemsetAsync(deg8, 0, (size_t)N * 8 * 4, stream);

  const int PB1 = (NCOLS * IN_DIM + 255) / 256;   // 288
  const int PB2 = (NCOLS * HID + 255) / 256;      // 144
  int DB = (E + 255) / 256;                       // 3125
  prep<<<PB1 + PB2 + DB, 256, 0, stream>>>(W1, root1, Bt1, W2, root2, Bt2,
                                           dstp, etype, deg8, E);
  cnt_scan<<<nb, SCAN_B, 0, stream>>>(deg8, rdeg8, cnt, bsum, N);
  scan2<<<1, 128, 0, stream>>>(bsum, nb);
  scan3<<<nb, SCAN_B, 0, stream>>>(cnt, bsum, offs, cursor, N, E);

  int GB = (N + 63) / 64;        // 782 gemm blocks
  int SB = (E + 255) / 256;      // 3125 scatter blocks
  gemm1_scatter<<<GB + SB, 256, 0, stream>>>(x, Bt1, b1, H, AGG1, N, GB,
                                             srcp, dstp, etype, cursor, ev, E);
  csr_agg<<<(N + 3) / 4, 256, 0, stream>>>(H, offs, ev, rdeg8, AGG1, N);
  gemm2_mfma<<<GB, 256, 0, stream>>>(AGG1, Bt2, b2, H, AGG2, N);
  csr_agg_final<<<(N + 3) / 4, 256, 0, stream>>>(H, offs, ev, rdeg8, AGG2,
                                                 Wl, bl, (float*)d_out, N);
}